// Round 3
// baseline (444.893 us; speedup 1.0000x reference)
//
#include <hip/hip_runtime.h>
#include <math.h>

#define NN 8
#define CC 64
#define HH 256
#define WW 256
#define K2 9
#define OC 72          // G*k2
#define BN_EPS 1e-5f
#define NBLK (NN * CC * 2)   // 1024 blocks: 2 half-image blocks per (n,c) plane

typedef float f4 __attribute__((ext_vector_type(4)));

// Single fused kernel: pool -> hand-rolled grid barrier -> lf (per-block) -> dyn 3x3 conv.
// 1024 blocks x 256 thr. __launch_bounds__(256,4) caps VGPR at 128 -> 4 blocks/CU
// capacity (LDS 308 B is no constraint) -> all 1024 blocks co-resident, so the
// atomic-counter spin barrier below cannot deadlock. (hipLaunchCooperativeKernel
// silently failed under the harness's graph capture in R2 -> all-zero output.)
__global__ __launch_bounds__(256, 4) void fused_kernel(
    const float* __restrict__ x,
    const float* __restrict__ conv_w,
    const float* __restrict__ gamma,
    const float* __restrict__ beta,
    const float* __restrict__ mean,
    const float* __restrict__ var,
    const float* __restrict__ lamb_l,
    const float* __restrict__ lamb_h,
    const float* __restrict__ ia,
    float* __restrict__ out,
    float* __restrict__ ws,
    unsigned* __restrict__ sync)   // sync[0]=arrival counter, sync[1]=flag (pre-zeroed)
{
    const int b    = blockIdx.x;
    const int nc   = b >> 1;           // (n,c) plane
    const int half = b & 1;            // which 128-row half
    const int lane = threadIdx.x & 63;
    const int wid  = threadIdx.x >> 6;
    const int c    = nc & (CC - 1);
    const int n    = nc >> 6;
    const int g    = c >> 3;           // C/G = 8

    const float* base  = x + (size_t)nc * (HH * WW);
    const f4*    hbase = (const f4*)(base + half * (HH / 2) * WW);

    // ---- phase 1: partial avg-pool over this half-image (128 rows) ----
    float s = 0.f;
#pragma unroll 8
    for (int i = threadIdx.x; i < (HH / 2) * WW / 4; i += 256) {
        f4 v = hbase[i];
        s += (v.x + v.y) + (v.z + v.w);
    }
    for (int off = 32; off > 0; off >>= 1) s += __shfl_down(s, off, 64);
    __shared__ float red[4];
    if (lane == 0) red[wid] = s;
    __syncthreads();
    if (threadIdx.x == 0) {
        float t = (red[0] + red[1]) + (red[2] + red[3]);
        // device-scope store: per-XCD L2s are not coherent (G16)
        __hip_atomic_store(&ws[b], t, __ATOMIC_RELEASE, __HIP_MEMORY_SCOPE_AGENT);
    }
    __syncthreads();

    // ---- hand-rolled grid barrier (all blocks co-resident by construction) ----
    if (threadIdx.x == 0) {
        unsigned prev = __hip_atomic_fetch_add(&sync[0], 1u, __ATOMIC_ACQ_REL,
                                               __HIP_MEMORY_SCOPE_AGENT);
        if (prev == NBLK - 1)
            __hip_atomic_store(&sync[1], 1u, __ATOMIC_RELEASE,
                               __HIP_MEMORY_SCOPE_AGENT);
        while (__hip_atomic_load(&sync[1], __ATOMIC_ACQUIRE,
                                 __HIP_MEMORY_SCOPE_AGENT) == 0u) {
            __builtin_amdgcn_s_sleep(8);
        }
    }
    __syncthreads();

    // ---- phase 2: rebuild pooled[n,*] and this group's 9 lf weights ----
    __shared__ float pl[CC];
    __shared__ float lfs[K2];
    if (threadIdx.x < CC) {
        float a0 = __hip_atomic_load(&ws[2 * (n * CC + threadIdx.x)],
                                     __ATOMIC_ACQUIRE, __HIP_MEMORY_SCOPE_AGENT);
        float a1 = __hip_atomic_load(&ws[2 * (n * CC + threadIdx.x) + 1],
                                     __ATOMIC_ACQUIRE, __HIP_MEMORY_SCOPE_AGENT);
        pl[threadIdx.x] = (a0 + a1) * (1.0f / (HH * WW));
    }
    __syncthreads();
    if (threadIdx.x < K2) {
        int oc = g * K2 + threadIdx.x;
        const float* pw = conv_w + oc * CC;
        float acc = 0.f;
#pragma unroll
        for (int cc2 = 0; cc2 < CC; ++cc2) acc += pl[cc2] * pw[cc2];
        float inv = gamma[oc] / sqrtf(var[oc] + BN_EPS);
        lfs[threadIdx.x] = tanhf((acc - mean[oc]) * inv + beta[oc]);
    }
    __syncthreads();

    const float w00 = lfs[0], w01 = lfs[1], w02 = lfs[2];
    const float w10 = lfs[3], w11 = lfs[4], w12 = lfs[5];
    const float w20 = lfs[6], w21 = lfs[7], w22 = lfs[8];
    const float ll    = lamb_l[c];
    const float lh1   = lamb_h[c] + 1.0f;
    const float iav   = ia[c];
    const float scale = iav + 1.0f;
    const float bias  = -iav * pl[c];

    float* outbase = out + (size_t)nc * (HH * WW);

    // ---- phase 3: dynamic 3x3 conv, 128 rows = 4 chunks of 32 (8 rows/wave) ----
    // x is L3-resident after phase 1; NT stores keep the write stream out of L3.
    for (int chunk = 0; chunk < 4; ++chunk) {
        const int r0 = half * (HH / 2) + chunk * 32 + wid * 8;
        f4    v[10];
        float L[10], R[10];
#pragma unroll
        for (int i = 0; i < 10; ++i) {
            int r = r0 - 1 + i;
            r = (r < 0) ? 1 : ((r > HH - 1) ? HH - 2 : r);   // reflection pad
            v[i] = ((const f4*)(base + (size_t)r * WW))[lane];
        }
#pragma unroll
        for (int i = 0; i < 10; ++i) {
            L[i] = __shfl_up(v[i].w, 1, 64);   if (lane == 0)  L[i] = v[i].y;
            R[i] = __shfl_down(v[i].x, 1, 64); if (lane == 63) R[i] = v[i].z;
        }
#pragma unroll
        for (int j = 0; j < 8; ++j) {
            const float t[6]  = {L[j],   v[j].x,   v[j].y,   v[j].z,   v[j].w,   R[j]};
            const float m[6]  = {L[j+1], v[j+1].x, v[j+1].y, v[j+1].z, v[j+1].w, R[j+1]};
            const float bb[6] = {L[j+2], v[j+2].x, v[j+2].y, v[j+2].z, v[j+2].w, R[j+2]};
            f4 o;
#pragma unroll
            for (int k = 0; k < 4; ++k) {
                float acc = w00 * t[k]  + w01 * t[k + 1]  + w02 * t[k + 2]
                          + w10 * m[k]  + w11 * m[k + 1]  + w12 * m[k + 2]
                          + w20 * bb[k] + w21 * bb[k + 1] + w22 * bb[k + 2];
                o[k] = ll * (scale * acc + bias) + lh1 * m[k + 1];
            }
            __builtin_nontemporal_store(o, ((f4*)(outbase + (size_t)(r0 + j) * WW)) + lane);
        }
    }
}

extern "C" void kernel_launch(void* const* d_in, const int* in_sizes, int n_in,
                              void* d_out, int out_size, void* d_ws, size_t ws_size,
                              hipStream_t stream) {
    const float* x      = (const float*)d_in[0];
    const float* conv_w = (const float*)d_in[1];
    const float* gamma  = (const float*)d_in[2];
    const float* beta   = (const float*)d_in[3];
    const float* mean   = (const float*)d_in[4];
    const float* var    = (const float*)d_in[5];
    const float* lamb_l = (const float*)d_in[6];
    const float* lamb_h = (const float*)d_in[7];
    const float* ia     = (const float*)d_in[8];
    float* out = (float*)d_out;
    float* ws  = (float*)d_ws;                        // NBLK partial sums
    unsigned* sync = (unsigned*)(ws + NBLK);          // [counter, flag]

    hipMemsetAsync(sync, 0, 2 * sizeof(unsigned), stream);  // graph-capture-safe
    fused_kernel<<<NBLK, 256, 0, stream>>>(x, conv_w, gamma, beta, mean, var,
                                           lamb_l, lamb_h, ia, out, ws, sync);
}

// Round 4
// 261.854 us; speedup vs baseline: 1.6990x; 1.6990x over previous
//
#include <hip/hip_runtime.h>
#include <math.h>

#define NN 8
#define CC 64
#define HH 256
#define WW 256
#define K2 9
#define OC 72          // G*k2
#define BN_EPS 1e-5f

typedef float f4 __attribute__((ext_vector_type(4)));

// ---------------- Kernel 1: adaptive avg pool (N,C,H,W) -> pooled[N*C] ----------
// 512 blocks x 1024 thr -> 2 blocks/CU = 32 waves/CU (full occ). Regular
// (caching) loads on purpose: this pass leaves x (128 MiB) resident in the
// 256 MiB L3, so main_kernel's x-reads are L3 hits (verified R3: fused kernel
// FETCH_SIZE = 134 MB = x read exactly once across both passes).
__global__ __launch_bounds__(1024) void pool_kernel(const float* __restrict__ x,
                                                    float* __restrict__ pooled) {
    int nc = blockIdx.x;                       // 0 .. N*C-1
    const f4* p4 = (const f4*)(x + (size_t)nc * (HH * WW));
    float s = 0.f;
#pragma unroll 4
    for (int i = threadIdx.x; i < (HH * WW) / 4; i += 1024) {
        f4 v = p4[i];
        s += (v.x + v.y) + (v.z + v.w);
    }
    for (int off = 32; off > 0; off >>= 1) s += __shfl_down(s, off, 64);
    __shared__ float smem[16];
    int lane = threadIdx.x & 63, wid = threadIdx.x >> 6;
    if (lane == 0) smem[wid] = s;
    __syncthreads();
    if (threadIdx.x < 16) {
        float t = smem[threadIdx.x];
        for (int off = 8; off > 0; off >>= 1) t += __shfl_down(t, off, 64);
        if (threadIdx.x == 0) pooled[nc] = t * (1.0f / (HH * WW));
    }
}

// ---------------- Kernel 2: per-block lf + dynamic 3x3 conv + affine combine ----
// lf_kernel folded in: each block rebuilds its image's pooled row (64 LDS loads)
// and computes its group's 9 dynamic-filter taps (576 FMA + 9 tanh) — noise vs
// the 1 MiB of pixel work. No device-scope atomics anywhere (R3 lesson: a
// hand-rolled grid barrier costs ~200 us in serialized cross-XCD atomics);
// the stream dependency between the two dispatches is the barrier.
// One wave handles 8 rows (loads 10), block = 4 waves = 32 rows,
// 8 blocks per (n,c) plane. Grid = 4096. NT stores keep the 131 MB write
// stream from evicting x out of L3.
__global__ __launch_bounds__(256) void main_kernel(const float* __restrict__ x,
                                                   const float* __restrict__ conv_w,
                                                   const float* __restrict__ gamma,
                                                   const float* __restrict__ beta,
                                                   const float* __restrict__ mean,
                                                   const float* __restrict__ var,
                                                   const float* __restrict__ lamb_l,
                                                   const float* __restrict__ lamb_h,
                                                   const float* __restrict__ ia,
                                                   const float* __restrict__ pooled,
                                                   float* __restrict__ out) {
    // Bijective XCD swizzle (grid 4096 = 8 chunks of 512): give each XCD a
    // contiguous run of planes so halo rows shared by adjacent row-blocks hit
    // the same per-XCD L2.
    const int bid  = (int)(blockIdx.x & 7) * 512 + (int)(blockIdx.x >> 3);
    const int wid  = threadIdx.x >> 6;          // wave 0..3
    const int lane = threadIdx.x & 63;
    const int nc   = bid >> 3;                  // 8 blocks per plane
    const int r0   = ((bid & 7) << 5) + (wid << 3);  // first output row (8/wave)
    const int c    = nc & (CC - 1);
    const int n    = nc >> 6;
    const int g    = c >> 3;                    // C/G = 8

    // ---- in-block lf: pooled row -> 9 dynamic taps for this block's group ----
    __shared__ float pl[CC];
    __shared__ float lfs[K2];
    if (threadIdx.x < CC) pl[threadIdx.x] = pooled[n * CC + threadIdx.x];
    __syncthreads();
    if (threadIdx.x < K2) {
        int oc = g * K2 + threadIdx.x;
        const float* pw = conv_w + oc * CC;
        float acc = 0.f;
#pragma unroll
        for (int cc2 = 0; cc2 < CC; ++cc2) acc += pl[cc2] * pw[cc2];
        float inv = gamma[oc] / sqrtf(var[oc] + BN_EPS);
        lfs[threadIdx.x] = tanhf((acc - mean[oc]) * inv + beta[oc]);
    }
    __syncthreads();

    const float w00 = lfs[0], w01 = lfs[1], w02 = lfs[2];
    const float w10 = lfs[3], w11 = lfs[4], w12 = lfs[5];
    const float w20 = lfs[6], w21 = lfs[7], w22 = lfs[8];
    const float ll    = lamb_l[c];
    const float lh1   = lamb_h[c] + 1.0f;
    const float iav   = ia[c];
    const float scale = iav + 1.0f;
    const float bias  = -iav * pl[c];

    const float* base    = x   + (size_t)nc * (HH * WW);
    float*       outbase = out + (size_t)nc * (HH * WW);

    f4    v[10];
    float L[10], R[10];
#pragma unroll
    for (int i = 0; i < 10; ++i) {
        int r = r0 - 1 + i;
        r = (r < 0) ? 1 : ((r > HH - 1) ? HH - 2 : r);   // reflection pad
        v[i] = ((const f4*)(base + (size_t)r * WW))[lane];
    }
#pragma unroll
    for (int i = 0; i < 10; ++i) {
        L[i] = __shfl_up(v[i].w, 1, 64);   if (lane == 0)  L[i] = v[i].y;
        R[i] = __shfl_down(v[i].x, 1, 64); if (lane == 63) R[i] = v[i].z;
    }
#pragma unroll
    for (int j = 0; j < 8; ++j) {
        const float t[6]  = {L[j],   v[j].x,   v[j].y,   v[j].z,   v[j].w,   R[j]};
        const float m[6]  = {L[j+1], v[j+1].x, v[j+1].y, v[j+1].z, v[j+1].w, R[j+1]};
        const float bb[6] = {L[j+2], v[j+2].x, v[j+2].y, v[j+2].z, v[j+2].w, R[j+2]};
        f4 o;
#pragma unroll
        for (int k = 0; k < 4; ++k) {
            float acc = w00 * t[k]  + w01 * t[k + 1]  + w02 * t[k + 2]
                      + w10 * m[k]  + w11 * m[k + 1]  + w12 * m[k + 2]
                      + w20 * bb[k] + w21 * bb[k + 1] + w22 * bb[k + 2];
            o[k] = ll * (scale * acc + bias) + lh1 * m[k + 1];
        }
        __builtin_nontemporal_store(o, ((f4*)(outbase + (size_t)(r0 + j) * WW)) + lane);
    }
}

extern "C" void kernel_launch(void* const* d_in, const int* in_sizes, int n_in,
                              void* d_out, int out_size, void* d_ws, size_t ws_size,
                              hipStream_t stream) {
    const float* x      = (const float*)d_in[0];
    const float* conv_w = (const float*)d_in[1];
    const float* gamma  = (const float*)d_in[2];
    const float* beta   = (const float*)d_in[3];
    const float* mean   = (const float*)d_in[4];
    const float* var    = (const float*)d_in[5];
    const float* lamb_l = (const float*)d_in[6];
    const float* lamb_h = (const float*)d_in[7];
    const float* ia     = (const float*)d_in[8];
    float* out = (float*)d_out;

    float* pooled = (float*)d_ws;              // N*C = 512 floats

    pool_kernel<<<NN * CC, 1024, 0, stream>>>(x, pooled);
    main_kernel<<<NN * CC * (HH / 32), 256, 0, stream>>>(x, conv_w, gamma, beta,
                                                         mean, var, lamb_l, lamb_h,
                                                         ia, pooled, out);
}